// Round 2
// baseline (193.807 us; speedup 1.0000x reference)
//
#include <hip/hip_runtime.h>
#include <stdint.h>

// pooled[b,p] = sum_{n in seg b} max_e ( proxy[p,e,:] . x[n,:] );  out = L2-normalized rows.
// P=128, E=32, D=64, B=1024 segments (len 128 each in bench; ragged handled).
//
// R1 structure: block = 1 segment (128 n) x all 128 p. 4 waves: (wn = n-half,
// wp = p-half). Wave: 2 n-tiles x 64 p of v_mfma_f32_32x32x16_bf16.
//  - zero-C trick: first K-step uses a live-forever zero C -> no per-p acc init
//  - max-over-e: max3-shaped in-lane tree (16 rows) + 1 shfl_xor(32)
//  - per-p col-reduction deferred: 1 LDS write/p, batched reduce + fused
//    L2-normalize at block end (sc_norm kernel deleted, no atomics)
// Register budget (target <=128 for 4 waves/SIMD): acc 32 + bfrag 32 + zero 16
// + A-dbuf 32 + misc ~15.

typedef short short8 __attribute__((ext_vector_type(8)));
typedef __bf16 bf16x8 __attribute__((ext_vector_type(8)));
typedef float floatx16 __attribute__((ext_vector_type(16)));

#define NELEM 32
#define DIM   64
#define NSEG  1024
#define PSTRIDE (NELEM * DIM) /* 2048 shorts per proxy set */
#define LROW 68               /* LDS row stride (floats): 64 + 4 pad, 16B-aligned */

__device__ __forceinline__ unsigned short f32_to_bf16_rne(float f) {
  union { float f; unsigned int u; } v; v.f = f;
  unsigned int r = v.u + 0x7fffu + ((v.u >> 16) & 1u);
  return (unsigned short)(r >> 16);
}

// Block 0: exclusive scan of segment lengths. Blocks 1..256: proxy fp32->bf16.
__global__ void sc_prep(const float* __restrict__ proxy,
                        const int* __restrict__ index,
                        short* __restrict__ pb,
                        int* __restrict__ offs) {
  const int bx = blockIdx.x, t = threadIdx.x;
  if (bx == 0) {
    __shared__ int lsum[256];
    const int base = t * 4;
    const int i0 = index[base + 0], i1 = index[base + 1];
    const int i2 = index[base + 2], i3 = index[base + 3];
    const int s = i0 + i1 + i2 + i3;
    lsum[t] = s;
    __syncthreads();
    for (int off = 1; off < 256; off <<= 1) {
      int v = (t >= off) ? lsum[t - off] : 0;
      __syncthreads();
      lsum[t] += v;
      __syncthreads();
    }
    const int ex = lsum[t] - s;
    offs[base + 0] = ex;
    offs[base + 1] = ex + i0;
    offs[base + 2] = ex + i0 + i1;
    offs[base + 3] = ex + i0 + i1 + i2;
    if (t == 255) offs[NSEG] = ex + s;
  } else {
    const int idx = ((bx - 1) * 256 + t) * 4; // 262144 proxy elems
    float4 v = *(const float4*)(proxy + idx);
    ushort4 o;
    o.x = f32_to_bf16_rne(v.x); o.y = f32_to_bf16_rne(v.y);
    o.z = f32_to_bf16_rne(v.z); o.w = f32_to_bf16_rne(v.w);
    *(ushort4*)(pb + idx) = o;
  }
}

__device__ __forceinline__ float max16(const floatx16& a) {
  // max3-shaped tree: 8 instrs if v_max3_f32 forms, depth ~3
  float r0 = fmaxf(fmaxf(a[0], a[1]), a[2]);
  float r1 = fmaxf(fmaxf(a[3], a[4]), a[5]);
  float r2 = fmaxf(fmaxf(a[6], a[7]), a[8]);
  float r3 = fmaxf(fmaxf(a[9], a[10]), a[11]);
  float r4 = fmaxf(fmaxf(a[12], a[13]), a[14]);
  float r5 = fmaxf(fmaxf(r0, r1), r2);
  float r6 = fmaxf(fmaxf(r3, r4), a[15]);
  return fmaxf(r5, r6);
}

__global__ __launch_bounds__(256, 4) void sc_main(
    const float* __restrict__ x,
    const short* __restrict__ pb,
    const int* __restrict__ offs,
    float* __restrict__ out) {
  __shared__ float buf[128 * LROW]; // [p][wn*32+col], accumulated across chunks
  __shared__ float red[4];

  const int b = blockIdx.x;
  const int tid = threadIdx.x;
  const int lane = tid & 63;
  const int w = tid >> 6;
  const int wn = w & 1;   // n-half: tiles at n = wn*64 + {0,32}
  const int wp = w >> 1;  // p-half: p in [wp*64, wp*64+64)
  const int l31 = lane & 31;
  const int h = lane >> 5;

  const int start = offs[b];
  const int len = offs[b + 1] - start;
  int nchunks = (len + 127) >> 7;
  if (nchunks < 1) nchunks = 1; // len==0: zero bfrags still store zeros to buf

  floatx16 zc; // permanently-zero C operand (never rewritten -> no per-p init)
#pragma unroll
  for (int r = 0; r < 16; ++r) zc[r] = 0.f;

  // A-frag lane base: pb[p][e=l31][k = 16kk + 8h + j]
  const short* abase = pb + (size_t)(wp * 64) * PSTRIDE + l31 * DIM + h * 8;

  for (int c = 0; c < nchunks; ++c) {
    const int c0 = c << 7;

    // B-frags: x rows (fp32->bf16 in-reg), n = c0 + wn*64 + t4*32 + l31
    short8 bfrag[2][4];
#pragma unroll
    for (int t4 = 0; t4 < 2; ++t4) {
      const int nl = c0 + wn * 64 + t4 * 32 + l31;
      const bool valid = (nl < len); // zero cols -> max_e(0)=0, adds nothing
      const float* xr = x + (size_t)(start + nl) * DIM + h * 8;
#pragma unroll
      for (int kk = 0; kk < 4; ++kk) {
        float4 f0 = make_float4(0.f, 0.f, 0.f, 0.f), f1 = f0;
        if (valid) {
          f0 = *(const float4*)(xr + kk * 16);
          f1 = *(const float4*)(xr + kk * 16 + 4);
        }
        short8 fr;
        fr[0] = (short)f32_to_bf16_rne(f0.x);
        fr[1] = (short)f32_to_bf16_rne(f0.y);
        fr[2] = (short)f32_to_bf16_rne(f0.z);
        fr[3] = (short)f32_to_bf16_rne(f0.w);
        fr[4] = (short)f32_to_bf16_rne(f1.x);
        fr[5] = (short)f32_to_bf16_rne(f1.y);
        fr[6] = (short)f32_to_bf16_rne(f1.z);
        fr[7] = (short)f32_to_bf16_rne(f1.w);
        bfrag[t4][kk] = fr;
      }
    }

    auto process = [&](int i, short8 (&cur)[4], short8 (&nxt)[4], bool pf) {
      if (pf) { // double-buffered A prefetch (covers ~200cy L2 latency)
        const short* ap = abase + (size_t)(i + 1) * PSTRIDE;
#pragma unroll
        for (int kk = 0; kk < 4; ++kk)
          nxt[kk] = *(const short8*)(ap + kk * 16);
      }
      floatx16 a0, a1;
#pragma unroll
      for (int kk = 0; kk < 4; ++kk) {
        bf16x8 a = __builtin_bit_cast(bf16x8, cur[kk]);
        bf16x8 b0 = __builtin_bit_cast(bf16x8, bfrag[0][kk]);
        bf16x8 b1 = __builtin_bit_cast(bf16x8, bfrag[1][kk]);
        if (kk == 0) {
          a0 = __builtin_amdgcn_mfma_f32_32x32x16_bf16(a, b0, zc, 0, 0, 0);
          a1 = __builtin_amdgcn_mfma_f32_32x32x16_bf16(a, b1, zc, 0, 0, 0);
        } else {
          a0 = __builtin_amdgcn_mfma_f32_32x32x16_bf16(a, b0, a0, 0, 0, 0);
          a1 = __builtin_amdgcn_mfma_f32_32x32x16_bf16(a, b1, a1, 0, 0, 0);
        }
      }
      // max over e: 16 in-lane rows + complementary 16 from lane^32
      float m0 = max16(a0);
      float m1 = max16(a1);
      m0 = fmaxf(m0, __shfl_xor(m0, 32, 64));
      m1 = fmaxf(m1, __shfl_xor(m1, 32, 64));
      const float s = m0 + m1; // partial sum over this wave's 2 n's for col l31
      const int p = wp * 64 + i;
      const int idx = p * LROW + wn * 32 + l31;
      if (h == 0) { // halves identical after xor-32 max; one writes
        float prev = (c == 0) ? 0.f : buf[idx];
        buf[idx] = prev + s;
      }
    };

    short8 afA[4], afB[4];
#pragma unroll
    for (int kk = 0; kk < 4; ++kk)
      afA[kk] = *(const short8*)(abase + kk * 16);
    for (int i = 0; i < 64; i += 2) { // unroll-2: compile-time dbuf index
      process(i, afA, afB, true);
      process(i + 1, afB, afA, i < 62);
    }
  }
  __syncthreads();

  // Batched col-reduction + fused L2-normalize. 2 threads per p.
  const int p2 = tid >> 1, part = tid & 1;
  const float* bp = buf + p2 * LROW + part * 32; // 272B row stride: 16B-aligned
  float4 v0 = *(const float4*)(bp + 0);
  float4 v1 = *(const float4*)(bp + 4);
  float4 v2 = *(const float4*)(bp + 8);
  float4 v3 = *(const float4*)(bp + 12);
  float4 v4 = *(const float4*)(bp + 16);
  float4 v5 = *(const float4*)(bp + 20);
  float4 v6 = *(const float4*)(bp + 24);
  float4 v7 = *(const float4*)(bp + 28);
  float s32 = ((v0.x + v0.y) + (v0.z + v0.w)) + ((v1.x + v1.y) + (v1.z + v1.w)) +
              ((v2.x + v2.y) + (v2.z + v2.w)) + ((v3.x + v3.y) + (v3.z + v3.w)) +
              ((v4.x + v4.y) + (v4.z + v4.w)) + ((v5.x + v5.y) + (v5.z + v5.w)) +
              ((v6.x + v6.y) + (v6.z + v6.w)) + ((v7.x + v7.y) + (v7.z + v7.w));
  const float s64 = s32 + __shfl_xor(s32, 1, 64); // pooled[b][p2]

  float sq = part ? 0.f : s64 * s64;
#pragma unroll
  for (int off = 1; off <= 32; off <<= 1) sq += __shfl_xor(sq, off, 64);
  if (lane == 0) red[w] = sq;
  __syncthreads();
  const float ss = (red[0] + red[1]) + (red[2] + red[3]);
  const float inv = 1.f / fmaxf(sqrtf(ss), 1e-12f);
  if (part == 0) out[(b << 7) + p2] = s64 * inv;
}

extern "C" void kernel_launch(void* const* d_in, const int* in_sizes, int n_in,
                              void* d_out, int out_size, void* d_ws, size_t ws_size,
                              hipStream_t stream) {
  (void)in_sizes; (void)n_in; (void)out_size; (void)ws_size;
  const float* x = (const float*)d_in[0];      // [N, 64] fp32
  const float* proxy = (const float*)d_in[1];  // [128, 32, 64] fp32
  const int* index = (const int*)d_in[2];      // [1024] int32
  float* out = (float*)d_out;                  // [1024, 128] fp32

  int* offs = (int*)d_ws;                      // (NSEG+1) ints
  short* pb = (short*)((char*)d_ws + 8192);    // 512 KB bf16 proxy

  sc_prep<<<257, 256, 0, stream>>>(proxy, index, pb, offs);
  sc_main<<<NSEG, 256, 0, stream>>>(x, pb, offs, out);
}

// Round 3
// 136.870 us; speedup vs baseline: 1.4160x; 1.4160x over previous
//
#include <hip/hip_runtime.h>
#include <stdint.h>

// pooled[b,p] = sum_{n in seg b} max_e ( proxy[p,e,:] . x[n,:] );  out = L2-normalized rows.
// P=128, E=32, D=64, B=1024 segments (len 128, 32-aligned starts in bench; ragged handled
// via global-32-aligned tiles + per-column epilogue masks).
//
// R2: - pb2 is FRAGMENT-MAJOR bf16 proxy: A-frag (p,kk) = contiguous 1KB, load =
//       uniform base + lane*16B (perfect coalescing; R1's pattern was a 32-line scatter
//       per instruction -> vmem stalls, MfmaUtil 20%).
//     - wave = 32 p x all 4 n-tiles: 16 MFMA/iter in 4 independent chains (one wave's
//       issue burst ~517 cyc nearly saturates the SIMD MFMA pipe; 2 waves/SIMD cover
//       each other's epilogue).
//     - zero-C trick (no acc init), max3-tree e-reduction, LDS-deferred col-reduction,
//       fused L2-normalize. __launch_bounds__(256,2): ~216 regs total, no squeeze.

typedef short short8 __attribute__((ext_vector_type(8)));
typedef __bf16 bf16x8 __attribute__((ext_vector_type(8)));
typedef float floatx16 __attribute__((ext_vector_type(16)));

#define NELEM 32
#define DIM   64
#define NSEG  1024
#define BROW  36   /* buf row stride in floats: 32 + 4 pad (16B-aligned rows) */

__device__ __forceinline__ unsigned short f32_to_bf16_rne(float f) {
  union { float f; unsigned int u; } v; v.f = f;
  unsigned int r = v.u + 0x7fffu + ((v.u >> 16) & 1u);
  return (unsigned short)(r >> 16);
}

// Block 0: exclusive scan of segment lengths -> offs[0..NSEG].
// Blocks 1..128: shuffle proxy fp32 -> fragment-major bf16 pb2:
//   pb2[ ((p*4 + kk)*64 + lane) * 8 ] = proxy[p][e=lane&31][kk*16 + (lane>>5)*8 .. +8]
__global__ void sc_prep(const float* __restrict__ proxy,
                        const int* __restrict__ index,
                        short* __restrict__ pb2,
                        int* __restrict__ offs) {
  const int bx = blockIdx.x, t = threadIdx.x;
  if (bx == 0) {
    __shared__ int lsum[256];
    const int base = t * 4;
    const int i0 = index[base + 0], i1 = index[base + 1];
    const int i2 = index[base + 2], i3 = index[base + 3];
    const int s = i0 + i1 + i2 + i3;
    lsum[t] = s;
    __syncthreads();
    for (int off = 1; off < 256; off <<= 1) {
      int v = (t >= off) ? lsum[t - off] : 0;
      __syncthreads();
      lsum[t] += v;
      __syncthreads();
    }
    const int ex = lsum[t] - s;
    offs[base + 0] = ex;
    offs[base + 1] = ex + i0;
    offs[base + 2] = ex + i0 + i1;
    offs[base + 3] = ex + i0 + i1 + i2;
    if (t == 255) offs[NSEG] = ex + s;
  } else {
    const int w = t >> 6, lane = t & 63;
    const int task = (bx - 1) * 4 + w;   // 0..511 = (p, kk)
    const int p = task >> 2, kk = task & 3;
    const int l31 = lane & 31, h = lane >> 5;
    const float* src = proxy + (size_t)p * (NELEM * DIM) + l31 * DIM + kk * 16 + h * 8;
    float4 f0 = *(const float4*)(src);
    float4 f1 = *(const float4*)(src + 4);
    short8 fr;
    fr[0] = (short)f32_to_bf16_rne(f0.x);
    fr[1] = (short)f32_to_bf16_rne(f0.y);
    fr[2] = (short)f32_to_bf16_rne(f0.z);
    fr[3] = (short)f32_to_bf16_rne(f0.w);
    fr[4] = (short)f32_to_bf16_rne(f1.x);
    fr[5] = (short)f32_to_bf16_rne(f1.y);
    fr[6] = (short)f32_to_bf16_rne(f1.z);
    fr[7] = (short)f32_to_bf16_rne(f1.w);
    *(short8*)(pb2 + ((size_t)task * 64 + lane) * 8) = fr;  // coalesced 1KB/wave
  }
}

__device__ __forceinline__ float max16(const floatx16& a) {
  float r0 = fmaxf(fmaxf(a[0], a[1]), a[2]);
  float r1 = fmaxf(fmaxf(a[3], a[4]), a[5]);
  float r2 = fmaxf(fmaxf(a[6], a[7]), a[8]);
  float r3 = fmaxf(fmaxf(a[9], a[10]), a[11]);
  float r4 = fmaxf(fmaxf(a[12], a[13]), a[14]);
  float r5 = fmaxf(fmaxf(r0, r1), r2);
  float r6 = fmaxf(fmaxf(r3, r4), a[15]);
  return fmaxf(r5, r6);
}

__global__ __launch_bounds__(256, 2) void sc_main(
    const float* __restrict__ x,
    const short* __restrict__ pb2,
    const int* __restrict__ offs,
    float* __restrict__ out,
    int nrows) {
  __shared__ float buf[128 * BROW];
  __shared__ float red[4];

  const int b = blockIdx.x;
  const int tid = threadIdx.x;
  const int lane = tid & 63;
  const int w = tid >> 6;     // wave w handles p = w + 4i, i in [0,32)
  const int l31 = lane & 31;
  const int h = lane >> 5;

  const int start = offs[b];
  const int end = offs[b + 1];
  const int len = end - start;
  const int first = start >> 5;
  const int ntiles = (len > 0) ? (((end + 31) >> 5) - first) : 0;
  const int npass = (ntiles + 3) >> 2;

  if (ntiles == 0) {
    for (int j = tid; j < 128 * BROW; j += 256) buf[j] = 0.f;
  }

  floatx16 zc;  // permanently-zero C operand
#pragma unroll
  for (int r = 0; r < 16; ++r) zc[r] = 0.f;

  // A lane base: frag(p=w+4i, kk) at pb2 + ((p*4+kk)*64 + lane)*8 shorts
  //            = abase + i*8192 + kk*512  (shorts)
  const short* abase = pb2 + ((size_t)w * 4 * 64 + lane) * 8;

  for (int pass = 0; pass < npass; ++pass) {
    // ---- B-frags: 4 global-aligned 32-row tiles, fp32 -> bf16 in-reg (once per
    // pass, amortized over 32 p-iterations). Out-of-segment columns masked in
    // the epilogue (garbage rows are safe: clamped addresses, per-col cndmask).
    short8 bfrag[4][4];
    bool vmask[4];
#pragma unroll
    for (int t4 = 0; t4 < 4; ++t4) {
      const int tile = first + pass * 4 + t4;
      const int n = tile * 32 + l31;
      vmask[t4] = (n >= start) && (n < end);
      int rn = n < nrows ? n : nrows - 1;  // clamp for safe load
      const float* xr = x + (size_t)rn * DIM + h * 8;
#pragma unroll
      for (int kk = 0; kk < 4; ++kk) {
        float4 f0 = *(const float4*)(xr + kk * 16);
        float4 f1 = *(const float4*)(xr + kk * 16 + 4);
        short8 fr;
        fr[0] = (short)f32_to_bf16_rne(f0.x);
        fr[1] = (short)f32_to_bf16_rne(f0.y);
        fr[2] = (short)f32_to_bf16_rne(f0.z);
        fr[3] = (short)f32_to_bf16_rne(f0.w);
        fr[4] = (short)f32_to_bf16_rne(f1.x);
        fr[5] = (short)f32_to_bf16_rne(f1.y);
        fr[6] = (short)f32_to_bf16_rne(f1.z);
        fr[7] = (short)f32_to_bf16_rne(f1.w);
        bfrag[t4][kk] = fr;
      }
    }

    auto process = [&](int i, short8 (&cur)[4], short8 (&nxt)[4], bool pf) {
      if (pf) {  // double-buffered coalesced A prefetch (next p = +4)
        const short* ap = abase + (size_t)(i + 1) * 8192;
#pragma unroll
        for (int kk = 0; kk < 4; ++kk)
          nxt[kk] = *(const short8*)(ap + kk * 512);
      }
      floatx16 a0, a1, a2, a3;  // 4 independent MFMA chains
#pragma unroll
      for (int kk = 0; kk < 4; ++kk) {
        bf16x8 a = __builtin_bit_cast(bf16x8, cur[kk]);
        bf16x8 b0 = __builtin_bit_cast(bf16x8, bfrag[0][kk]);
        bf16x8 b1 = __builtin_bit_cast(bf16x8, bfrag[1][kk]);
        bf16x8 b2 = __builtin_bit_cast(bf16x8, bfrag[2][kk]);
        bf16x8 b3 = __builtin_bit_cast(bf16x8, bfrag[3][kk]);
        if (kk == 0) {
          a0 = __builtin_amdgcn_mfma_f32_32x32x16_bf16(a, b0, zc, 0, 0, 0);
          a1 = __builtin_amdgcn_mfma_f32_32x32x16_bf16(a, b1, zc, 0, 0, 0);
          a2 = __builtin_amdgcn_mfma_f32_32x32x16_bf16(a, b2, zc, 0, 0, 0);
          a3 = __builtin_amdgcn_mfma_f32_32x32x16_bf16(a, b3, zc, 0, 0, 0);
        } else {
          a0 = __builtin_amdgcn_mfma_f32_32x32x16_bf16(a, b0, a0, 0, 0, 0);
          a1 = __builtin_amdgcn_mfma_f32_32x32x16_bf16(a, b1, a1, 0, 0, 0);
          a2 = __builtin_amdgcn_mfma_f32_32x32x16_bf16(a, b2, a2, 0, 0, 0);
          a3 = __builtin_amdgcn_mfma_f32_32x32x16_bf16(a, b3, a3, 0, 0, 0);
        }
      }
      // max over e: 16 in-lane rows + complementary 16 from lane^32
      float m0 = max16(a0), m1 = max16(a1), m2 = max16(a2), m3 = max16(a3);
      m0 = fmaxf(m0, __shfl_xor(m0, 32, 64));
      m1 = fmaxf(m1, __shfl_xor(m1, 32, 64));
      m2 = fmaxf(m2, __shfl_xor(m2, 32, 64));
      m3 = fmaxf(m3, __shfl_xor(m3, 32, 64));
      // mask out-of-segment columns (select, not multiply: garbage may be NaN/inf)
      m0 = vmask[0] ? m0 : 0.f;
      m1 = vmask[1] ? m1 : 0.f;
      m2 = vmask[2] ? m2 : 0.f;
      m3 = vmask[3] ? m3 : 0.f;
      const float s = (m0 + m1) + (m2 + m3);  // partial sum over 4 tiles, col l31
      if (h == 0) {
        const int p = w + 4 * i;
        const int idx = p * BROW + l31;
        float prev = (pass == 0) ? 0.f : buf[idx];
        buf[idx] = prev + s;
      }
    };

    short8 afA[4], afB[4];
#pragma unroll
    for (int kk = 0; kk < 4; ++kk)
      afA[kk] = *(const short8*)(abase + kk * 512);
    for (int i = 0; i < 32; i += 2) {  // unroll-2: compile-time dbuf index
      process(i, afA, afB, true);
      process(i + 1, afB, afA, i < 30);
    }
  }
  __syncthreads();

  // Batched 32-col reduction + fused L2-normalize. 2 threads per p.
  const int p2 = tid >> 1, part = tid & 1;
  const float* bp = buf + p2 * BROW + part * 16;
  float4 v0 = *(const float4*)(bp + 0);
  float4 v1 = *(const float4*)(bp + 4);
  float4 v2 = *(const float4*)(bp + 8);
  float4 v3 = *(const float4*)(bp + 12);
  float s16 = ((v0.x + v0.y) + (v0.z + v0.w)) + ((v1.x + v1.y) + (v1.z + v1.w)) +
              ((v2.x + v2.y) + (v2.z + v2.w)) + ((v3.x + v3.y) + (v3.z + v3.w));
  const float s32 = s16 + __shfl_xor(s16, 1, 64);  // pooled[b][p2]

  float sq = part ? 0.f : s32 * s32;
#pragma unroll
  for (int off = 1; off <= 32; off <<= 1) sq += __shfl_xor(sq, off, 64);
  if (lane == 0) red[w] = sq;
  __syncthreads();
  const float ss = (red[0] + red[1]) + (red[2] + red[3]);
  const float inv = 1.f / fmaxf(sqrtf(ss), 1e-12f);
  if (part == 0) out[(b << 7) + p2] = s32 * inv;
}

extern "C" void kernel_launch(void* const* d_in, const int* in_sizes, int n_in,
                              void* d_out, int out_size, void* d_ws, size_t ws_size,
                              hipStream_t stream) {
  (void)n_in; (void)out_size; (void)ws_size;
  const float* x = (const float*)d_in[0];      // [N, 64] fp32
  const float* proxy = (const float*)d_in[1];  // [128, 32, 64] fp32
  const int* index = (const int*)d_in[2];      // [1024] int32
  float* out = (float*)d_out;                  // [1024, 128] fp32
  const int nrows = in_sizes[0] / DIM;

  int* offs = (int*)d_ws;                      // (NSEG+1) ints
  short* pb2 = (short*)((char*)d_ws + 8192);   // 512 KB fragment-major bf16 proxy

  sc_prep<<<129, 256, 0, stream>>>(proxy, index, pb2, offs);
  sc_main<<<NSEG, 256, 0, stream>>>(x, pb2, offs, out, nrows);
}